// Round 1
// baseline (1044.096 us; speedup 1.0000x reference)
//
#include <hip/hip_runtime.h>

#define N_NODES 100000
#define N_EDGES 1600000

// ---------------- degree + norm ----------------

__global__ void deg_kernel(const int* __restrict__ src, const int* __restrict__ dst,
                           float* __restrict__ dout, float* __restrict__ din, int E) {
    int e = blockIdx.x * blockDim.x + threadIdx.x;
    if (e < E) {
        atomicAdd(&dout[src[e]], 1.0f);
        atomicAdd(&din[dst[e]], 1.0f);
    }
}

__global__ void norm_kernel(float* __restrict__ dout, float* __restrict__ din, int n) {
    int i = blockIdx.x * blockDim.x + threadIdx.x;
    if (i < n) {
        dout[i] = 1.0f / sqrtf(fmaxf(dout[i], 1.0f));
        din[i]  = 1.0f / sqrtf(fmaxf(din[i], 1.0f));
    }
}

// ---------------- GEMM1: h1 = (x * out_norm) @ W1   [N,256]@[256,64] ----------------
// 64x64 tile, BK=16, 256 threads, 4x4 register micro-tile per thread.

__global__ __launch_bounds__(256) void gemm1_kernel(
    const float* __restrict__ x, const float* __restrict__ W,
    const float* __restrict__ onorm, float* __restrict__ h, int n) {
    __shared__ float As[16][64];  // [k][row]
    __shared__ float Ws[16][64];  // [k][col]
    const int tid = threadIdx.x;
    const int tx = tid & 15;   // col group (4 cols)
    const int ty = tid >> 4;   // row group (4 rows)
    const int rowBase = blockIdx.x * 64;

    // A-load assignment (fixed across K chunks)
    const int lr  = tid >> 2;         // 0..63  row within tile
    const int lk  = (tid & 3) * 4;    // 0,4,8,12 k within chunk
    const int lrow = rowBase + lr;
    const bool lvalid = (lrow < n);
    const float lscale = lvalid ? onorm[lrow] : 0.0f;
    // W-load assignment
    const int wk = tid >> 4;          // 0..15
    const int wc = (tid & 15) * 4;    // 0..60

    float acc[4][4] = {};

    for (int k0 = 0; k0 < 256; k0 += 16) {
        float4 v = make_float4(0.f, 0.f, 0.f, 0.f);
        if (lvalid) v = *(const float4*)(x + (size_t)lrow * 256 + k0 + lk);
        As[lk + 0][lr] = v.x * lscale;
        As[lk + 1][lr] = v.y * lscale;
        As[lk + 2][lr] = v.z * lscale;
        As[lk + 3][lr] = v.w * lscale;
        *(float4*)&Ws[wk][wc] = *(const float4*)(W + (size_t)(k0 + wk) * 64 + wc);
        __syncthreads();
#pragma unroll
        for (int k = 0; k < 16; ++k) {
            float4 a = *(const float4*)&As[k][ty * 4];
            float4 b = *(const float4*)&Ws[k][tx * 4];
            float av[4] = {a.x, a.y, a.z, a.w};
            float bv[4] = {b.x, b.y, b.z, b.w};
#pragma unroll
            for (int i = 0; i < 4; ++i)
#pragma unroll
                for (int j = 0; j < 4; ++j) acc[i][j] += av[i] * bv[j];
        }
        __syncthreads();
    }
#pragma unroll
    for (int i = 0; i < 4; ++i) {
        int row = rowBase + ty * 4 + i;
        if (row < n) {
            *(float4*)(h + (size_t)row * 64 + tx * 4) =
                make_float4(acc[i][0], acc[i][1], acc[i][2], acc[i][3]);
        }
    }
}

// ---------------- scatter layer1: agg1[dst] += h1[src], 64 feats/edge ----------------

__global__ void scatter1_kernel(const int* __restrict__ src, const int* __restrict__ dst,
                                const float* __restrict__ h, float* __restrict__ agg, int E) {
    int idx = blockIdx.x * blockDim.x + threadIdx.x;
    int e = idx >> 6;
    int f = idx & 63;
    if (e < E) {
        int s = src[e];
        int d = dst[e];
        atomicAdd(&agg[(size_t)d * 64 + f], h[(size_t)s * 64 + f]);
    }
}

// ---------------- GEMM2: h2 = ((agg1*in_norm + b1) * out_norm) @ W2   [N,64]@[64,40] ----

__global__ __launch_bounds__(256) void gemm2_kernel(
    const float* __restrict__ agg, const float* __restrict__ W2,
    const float* __restrict__ b1, const float* __restrict__ inorm,
    const float* __restrict__ onorm, float* __restrict__ h2, int n) {
    __shared__ float Ws[64 * 40];
    int tid = threadIdx.x;
    for (int i = tid; i < 64 * 40; i += 256) Ws[i] = W2[i];
    __syncthreads();
    int lane = tid & 63;
    int wave = tid >> 6;
    int step = gridDim.x * 4;
    for (int row = blockIdx.x * 4 + wave; row < n; row += step) {
        float so  = onorm[row];
        float s12 = inorm[row] * so;
        const float* ar = agg + (size_t)row * 64;
        if (lane < 40) {
            float acc = 0.f;
#pragma unroll
            for (int k = 0; k < 64; ++k) {
                float xv = ar[k] * s12 + b1[k] * so;
                acc += xv * Ws[k * 40 + lane];
            }
            h2[(size_t)row * 40 + lane] = acc;
        }
    }
}

// ---------------- scatter layer2: out[dst] += h2[src], 40 feats/edge ----------------

__global__ void scatter2_kernel(const int* __restrict__ src, const int* __restrict__ dst,
                                const float* __restrict__ h2, float* __restrict__ out, int E) {
    int idx = blockIdx.x * blockDim.x + threadIdx.x;
    int e = idx >> 6;
    int f = idx & 63;
    if (e < E && f < 40) {
        atomicAdd(&out[(size_t)dst[e] * 40 + f], h2[(size_t)src[e] * 40 + f]);
    }
}

// ---------------- epilogue: out = out * in_norm + b2 ----------------

__global__ void final_kernel(float* __restrict__ out, const float* __restrict__ inorm,
                             const float* __restrict__ b2, int total) {
    int idx = blockIdx.x * blockDim.x + threadIdx.x;
    if (idx < total) {
        int i = idx / 40;
        int f = idx - i * 40;
        out[idx] = out[idx] * inorm[i] + b2[f];
    }
}

extern "C" void kernel_launch(void* const* d_in, const int* in_sizes, int n_in,
                              void* d_out, int out_size, void* d_ws, size_t ws_size,
                              hipStream_t stream) {
    const float* x  = (const float*)d_in[0];
    const int* src  = (const int*)d_in[1];
    const int* dst  = (const int*)d_in[2];
    const float* W1 = (const float*)d_in[3];
    const float* b1 = (const float*)d_in[4];
    const float* W2 = (const float*)d_in[5];
    const float* b2 = (const float*)d_in[6];
    float* out = (float*)d_out;

    float* ws = (float*)d_ws;
    float* deg_out = ws;                                  // N (becomes out_norm)
    float* deg_in  = ws + N_NODES;                        // N (becomes in_norm)
    float* h1      = ws + 2 * N_NODES;                    // N*64 (reused as h2)
    float* agg1    = ws + 2 * N_NODES + (size_t)N_NODES * 64;  // N*64
    float* h2 = h1;

    hipMemsetAsync(deg_out, 0, 2 * N_NODES * sizeof(float), stream);
    hipMemsetAsync(agg1, 0, (size_t)N_NODES * 64 * sizeof(float), stream);
    hipMemsetAsync(out, 0, (size_t)N_NODES * 40 * sizeof(float), stream);

    deg_kernel<<<(N_EDGES + 255) / 256, 256, 0, stream>>>(src, dst, deg_out, deg_in, N_EDGES);
    norm_kernel<<<(N_NODES + 255) / 256, 256, 0, stream>>>(deg_out, deg_in, N_NODES);

    gemm1_kernel<<<(N_NODES + 63) / 64, 256, 0, stream>>>(x, W1, deg_out, h1, N_NODES);

    scatter1_kernel<<<(N_EDGES * 64) / 256, 256, 0, stream>>>(src, dst, h1, agg1, N_EDGES);

    gemm2_kernel<<<2048, 256, 0, stream>>>(agg1, W2, b1, deg_in, deg_out, h2, N_NODES);

    scatter2_kernel<<<(N_EDGES * 64) / 256, 256, 0, stream>>>(src, dst, h2, out, N_EDGES);

    final_kernel<<<(N_NODES * 40 + 255) / 256, 256, 0, stream>>>(out, deg_in, b2, N_NODES * 40);
}

// Round 2
// 600.341 us; speedup vs baseline: 1.7392x; 1.7392x over previous
//
#include <hip/hip_runtime.h>

#define N_NODES 100000
#define N_EDGES 1600000
#define NB ((N_NODES + 255) / 256)   // 391 scan blocks

// ---------------- integer degree count ----------------

__global__ void deg_kernel(const int* __restrict__ src, const int* __restrict__ dst,
                           int* __restrict__ odeg, int* __restrict__ ideg, int E) {
    int e = blockIdx.x * blockDim.x + threadIdx.x;
    if (e < E) {
        atomicAdd(&odeg[src[e]], 1);
        atomicAdd(&ideg[dst[e]], 1);
    }
}

__global__ void norm_kernel(const int* __restrict__ odeg, const int* __restrict__ ideg,
                            float* __restrict__ onorm, float* __restrict__ inorm, int n) {
    int i = blockIdx.x * blockDim.x + threadIdx.x;
    if (i < n) {
        onorm[i] = 1.0f / sqrtf((float)max(odeg[i], 1));
        inorm[i] = 1.0f / sqrtf((float)max(ideg[i], 1));
    }
}

// ---------------- prefix scan over in-degrees -> CSR row_start ----------------

__global__ void scan1_kernel(const int* __restrict__ cnt, int* __restrict__ bsum) {
    __shared__ int sm[256];
    int i = blockIdx.x * 256 + threadIdx.x;
    sm[threadIdx.x] = (i < N_NODES) ? cnt[i] : 0;
    __syncthreads();
    for (int s = 128; s > 0; s >>= 1) {
        if (threadIdx.x < s) sm[threadIdx.x] += sm[threadIdx.x + s];
        __syncthreads();
    }
    if (threadIdx.x == 0) bsum[blockIdx.x] = sm[0];
}

__global__ void scan2_kernel(const int* __restrict__ bsum, int* __restrict__ boff) {
    __shared__ int sm[512];
    int t = threadIdx.x;
    int mine = (t < NB) ? bsum[t] : 0;
    sm[t] = mine;
    __syncthreads();
    for (int s = 1; s < 512; s <<= 1) {
        int v = (t >= s) ? sm[t - s] : 0;
        __syncthreads();
        sm[t] += v;
        __syncthreads();
    }
    if (t < NB) boff[t] = sm[t] - mine;   // exclusive
}

__global__ void scan3_kernel(const int* __restrict__ cnt, const int* __restrict__ boff,
                             int* __restrict__ rs) {
    __shared__ int sm[256];
    int i = blockIdx.x * 256 + threadIdx.x;
    int v = (i < N_NODES) ? cnt[i] : 0;
    sm[threadIdx.x] = v;
    __syncthreads();
    for (int s = 1; s < 256; s <<= 1) {
        int u = (threadIdx.x >= s) ? sm[threadIdx.x - s] : 0;
        __syncthreads();
        sm[threadIdx.x] += u;
        __syncthreads();
    }
    if (i < N_NODES) rs[i] = boff[blockIdx.x] + sm[threadIdx.x] - v;  // exclusive
    if (i == 0) rs[N_NODES] = N_EDGES;
}

// ---------------- edge placement into CSR ----------------

__global__ void place_kernel(const int* __restrict__ src, const int* __restrict__ dst,
                             const int* __restrict__ rs, int* __restrict__ cursor,
                             int* __restrict__ sorted_src, int E) {
    int e = blockIdx.x * blockDim.x + threadIdx.x;
    if (e < E) {
        int d = dst[e];
        int pos = rs[d] + atomicAdd(&cursor[d], 1);
        sorted_src[pos] = src[e];
    }
}

// ---------------- GEMM1: h1 = (x * out_norm) @ W1   [N,256]@[256,64] ----------------

__global__ __launch_bounds__(256) void gemm1_kernel(
    const float* __restrict__ x, const float* __restrict__ W,
    const float* __restrict__ onorm, float* __restrict__ h, int n) {
    __shared__ float As[16][64];
    __shared__ float Ws[16][64];
    const int tid = threadIdx.x;
    const int tx = tid & 15;
    const int ty = tid >> 4;
    const int rowBase = blockIdx.x * 64;

    const int lr = tid >> 2;
    const int lk = (tid & 3) * 4;
    const int lrow = rowBase + lr;
    const bool lvalid = (lrow < n);
    const float lscale = lvalid ? onorm[lrow] : 0.0f;
    const int wk = tid >> 4;
    const int wc = (tid & 15) * 4;

    float acc[4][4] = {};

    for (int k0 = 0; k0 < 256; k0 += 16) {
        float4 v = make_float4(0.f, 0.f, 0.f, 0.f);
        if (lvalid) v = *(const float4*)(x + (size_t)lrow * 256 + k0 + lk);
        As[lk + 0][lr] = v.x * lscale;
        As[lk + 1][lr] = v.y * lscale;
        As[lk + 2][lr] = v.z * lscale;
        As[lk + 3][lr] = v.w * lscale;
        *(float4*)&Ws[wk][wc] = *(const float4*)(W + (size_t)(k0 + wk) * 64 + wc);
        __syncthreads();
#pragma unroll
        for (int k = 0; k < 16; ++k) {
            float4 a = *(const float4*)&As[k][ty * 4];
            float4 b = *(const float4*)&Ws[k][tx * 4];
            float av[4] = {a.x, a.y, a.z, a.w};
            float bv[4] = {b.x, b.y, b.z, b.w};
#pragma unroll
            for (int i = 0; i < 4; ++i)
#pragma unroll
                for (int j = 0; j < 4; ++j) acc[i][j] += av[i] * bv[j];
        }
        __syncthreads();
    }
#pragma unroll
    for (int i = 0; i < 4; ++i) {
        int row = rowBase + ty * 4 + i;
        if (row < n) {
            *(float4*)(h + (size_t)row * 64 + tx * 4) =
                make_float4(acc[i][0], acc[i][1], acc[i][2], acc[i][3]);
        }
    }
}

// ---------------- aggregate layer1: one wave per node, 64 feats ----------------

__global__ __launch_bounds__(256) void agg64_kernel(
    const int* __restrict__ rs, const int* __restrict__ ss,
    const float* __restrict__ h, float* __restrict__ agg, int n) {
    int wave = (blockIdx.x * blockDim.x + threadIdx.x) >> 6;
    int lane = threadIdx.x & 63;
    if (wave >= n) return;
    int beg = rs[wave], end = rs[wave + 1];
    float a0 = 0.f, a1 = 0.f, a2 = 0.f, a3 = 0.f;
    int j = beg;
    for (; j + 4 <= end; j += 4) {
        int s0 = ss[j], s1 = ss[j + 1], s2 = ss[j + 2], s3 = ss[j + 3];
        a0 += h[(size_t)s0 * 64 + lane];
        a1 += h[(size_t)s1 * 64 + lane];
        a2 += h[(size_t)s2 * 64 + lane];
        a3 += h[(size_t)s3 * 64 + lane];
    }
    for (; j < end; ++j) a0 += h[(size_t)ss[j] * 64 + lane];
    agg[(size_t)wave * 64 + lane] = (a0 + a1) + (a2 + a3);
}

// ---------------- GEMM2: h2 = ((agg*in_norm + b1) * out_norm) @ W2  [N,64]@[64,40] ----

__global__ __launch_bounds__(256) void gemm2_kernel(
    const float* __restrict__ agg, const float* __restrict__ W2,
    const float* __restrict__ b1, const float* __restrict__ inorm,
    const float* __restrict__ onorm, float* __restrict__ h2, int n) {
    __shared__ float Ws[64 * 40];
    int tid = threadIdx.x;
    for (int i = tid; i < 64 * 40; i += 256) Ws[i] = W2[i];
    __syncthreads();
    int lane = tid & 63;
    int wave = tid >> 6;
    int step = gridDim.x * 4;
    for (int row = blockIdx.x * 4 + wave; row < n; row += step) {
        float so  = onorm[row];
        float s12 = inorm[row] * so;
        const float* ar = agg + (size_t)row * 64;
        if (lane < 40) {
            float acc = 0.f;
#pragma unroll
            for (int k = 0; k < 64; ++k) {
                float xv = ar[k] * s12 + b1[k] * so;
                acc += xv * Ws[k * 40 + lane];
            }
            h2[(size_t)row * 40 + lane] = acc;
        }
    }
}

// ---------------- aggregate layer2 + epilogue: out = agg2 * in_norm + b2 ----------------

__global__ __launch_bounds__(256) void agg40_kernel(
    const int* __restrict__ rs, const int* __restrict__ ss,
    const float* __restrict__ h2, const float* __restrict__ inorm,
    const float* __restrict__ b2, float* __restrict__ out, int n) {
    int wave = (blockIdx.x * blockDim.x + threadIdx.x) >> 6;
    int lane = threadIdx.x & 63;
    if (wave >= n) return;
    int beg = rs[wave], end = rs[wave + 1];
    if (lane < 40) {
        float a0 = 0.f, a1 = 0.f, a2 = 0.f, a3 = 0.f;
        int j = beg;
        for (; j + 4 <= end; j += 4) {
            int s0 = ss[j], s1 = ss[j + 1], s2 = ss[j + 2], s3 = ss[j + 3];
            a0 += h2[(size_t)s0 * 40 + lane];
            a1 += h2[(size_t)s1 * 40 + lane];
            a2 += h2[(size_t)s2 * 40 + lane];
            a3 += h2[(size_t)s3 * 40 + lane];
        }
        for (; j < end; ++j) a0 += h2[(size_t)ss[j] * 40 + lane];
        out[(size_t)wave * 40 + lane] = ((a0 + a1) + (a2 + a3)) * inorm[wave] + b2[lane];
    }
}

extern "C" void kernel_launch(void* const* d_in, const int* in_sizes, int n_in,
                              void* d_out, int out_size, void* d_ws, size_t ws_size,
                              hipStream_t stream) {
    const float* x  = (const float*)d_in[0];
    const int* src  = (const int*)d_in[1];
    const int* dst  = (const int*)d_in[2];
    const float* W1 = (const float*)d_in[3];
    const float* b1 = (const float*)d_in[4];
    const float* W2 = (const float*)d_in[5];
    const float* b2 = (const float*)d_in[6];
    float* out = (float*)d_out;

    char* wsb = (char*)d_ws;
    size_t off = 0;
    auto alloc = [&](size_t bytes) { char* p = wsb + off; off += (bytes + 255) & ~size_t(255); return p; };

    int*   odeg    = (int*)  alloc(N_NODES * 4);
    int*   ideg    = (int*)  alloc(N_NODES * 4);
    int*   cursor  = (int*)  alloc(N_NODES * 4);
    float* onorm   = (float*)alloc(N_NODES * 4);
    float* inorm   = (float*)alloc(N_NODES * 4);
    int*   rs      = (int*)  alloc((N_NODES + 1) * 4);
    int*   bsum    = (int*)  alloc(512 * 4);
    int*   boff    = (int*)  alloc(512 * 4);
    int*   ssrc    = (int*)  alloc((size_t)N_EDGES * 4);
    float* h1      = (float*)alloc((size_t)N_NODES * 64 * 4);  // reused as h2 (N*40)
    float* agg1    = (float*)alloc((size_t)N_NODES * 64 * 4);
    float* h2 = h1;

    // zero the three counter arrays (they are adjacent allocations)
    hipMemsetAsync(odeg, 0, 3 * ((N_NODES * 4 + 255) & ~size_t(255)), stream);

    deg_kernel<<<(N_EDGES + 255) / 256, 256, 0, stream>>>(src, dst, odeg, ideg, N_EDGES);
    norm_kernel<<<(N_NODES + 255) / 256, 256, 0, stream>>>(odeg, ideg, onorm, inorm, N_NODES);

    scan1_kernel<<<NB, 256, 0, stream>>>(ideg, bsum);
    scan2_kernel<<<1, 512, 0, stream>>>(bsum, boff);
    scan3_kernel<<<NB, 256, 0, stream>>>(ideg, boff, rs);

    place_kernel<<<(N_EDGES + 255) / 256, 256, 0, stream>>>(src, dst, rs, cursor, ssrc, N_EDGES);

    gemm1_kernel<<<(N_NODES + 63) / 64, 256, 0, stream>>>(x, W1, onorm, h1, N_NODES);

    agg64_kernel<<<(N_NODES + 3) / 4, 256, 0, stream>>>(rs, ssrc, h1, agg1, N_NODES);

    gemm2_kernel<<<2048, 256, 0, stream>>>(agg1, W2, b1, inorm, onorm, h2, N_NODES);

    agg40_kernel<<<(N_NODES + 3) / 4, 256, 0, stream>>>(rs, ssrc, h2, inorm, b2, out, N_NODES);
}

// Round 3
// 484.847 us; speedup vs baseline: 2.1535x; 1.2382x over previous
//
#include <hip/hip_runtime.h>

#define N_NODES 100000
#define N_EDGES 1600000
#define NBUCK 391            // ceil(N_NODES / 256)
#define HBLK 128             // blocks for histogram/scatter kernels

// ---------------- K1: coarse histograms of dst>>8 and src>>8 ----------------

__global__ __launch_bounds__(256) void coarse_hist_kernel(
    const int* __restrict__ src, const int* __restrict__ dst,
    int* __restrict__ gHD, int* __restrict__ gHS) {
    __shared__ int hd[NBUCK], hs[NBUCK];
    for (int i = threadIdx.x; i < NBUCK; i += 256) { hd[i] = 0; hs[i] = 0; }
    __syncthreads();
    for (int e = blockIdx.x * 256 + threadIdx.x; e < N_EDGES; e += HBLK * 256) {
        atomicAdd(&hd[dst[e] >> 8], 1);
        atomicAdd(&hs[src[e] >> 8], 1);
    }
    __syncthreads();
    for (int i = threadIdx.x; i < NBUCK; i += 256) {
        if (hd[i]) atomicAdd(&gHD[i], hd[i]);
        if (hs[i]) atomicAdd(&gHS[i], hs[i]);
    }
}

// ---------------- K2: scan coarse bins -> bucket bases ----------------

__global__ void coarse_scan_kernel(const int* __restrict__ gHD, const int* __restrict__ gHS,
                                   int* __restrict__ dBase, int* __restrict__ sBase) {
    __shared__ int sd[512], se[512];
    int t = threadIdx.x;
    int vd = (t < NBUCK) ? gHD[t] : 0;
    int vs = (t < NBUCK) ? gHS[t] : 0;
    sd[t] = vd; se[t] = vs;
    __syncthreads();
    for (int s = 1; s < 512; s <<= 1) {
        int ud = (t >= s) ? sd[t - s] : 0;
        int us = (t >= s) ? se[t - s] : 0;
        __syncthreads();
        sd[t] += ud; se[t] += us;
        __syncthreads();
    }
    if (t < NBUCK) { dBase[t] = sd[t] - vd; sBase[t] = se[t] - vs; }
    if (t == 0) { dBase[NBUCK] = N_EDGES; sBase[NBUCK] = N_EDGES; }
}

// ---------------- K3a: scatter edges into dst-buckets ----------------

__global__ __launch_bounds__(256) void scatter_dst_kernel(
    const int* __restrict__ src, const int* __restrict__ dst,
    const int* __restrict__ dBase, int* __restrict__ dRes,
    int* __restrict__ bsrc, unsigned char* __restrict__ bdlo) {
    __shared__ int h[NBUCK];
    __shared__ int cur[NBUCK];
    for (int i = threadIdx.x; i < NBUCK; i += 256) h[i] = 0;
    __syncthreads();
    for (int e = blockIdx.x * 256 + threadIdx.x; e < N_EDGES; e += HBLK * 256)
        atomicAdd(&h[dst[e] >> 8], 1);
    __syncthreads();
    for (int i = threadIdx.x; i < NBUCK; i += 256) {
        int c = h[i];
        cur[i] = dBase[i] + (c ? atomicAdd(&dRes[i], c) : 0);
    }
    __syncthreads();
    for (int e = blockIdx.x * 256 + threadIdx.x; e < N_EDGES; e += HBLK * 256) {
        int d = dst[e];
        int p = atomicAdd(&cur[d >> 8], 1);   // LDS atomic
        bsrc[p] = src[e];
        bdlo[p] = (unsigned char)(d & 255);
    }
}

// ---------------- K3b: scatter src low-bytes into src-buckets ----------------

__global__ __launch_bounds__(256) void scatter_src_kernel(
    const int* __restrict__ src,
    const int* __restrict__ sBase, int* __restrict__ sRes,
    unsigned char* __restrict__ bslo) {
    __shared__ int h[NBUCK];
    __shared__ int cur[NBUCK];
    for (int i = threadIdx.x; i < NBUCK; i += 256) h[i] = 0;
    __syncthreads();
    for (int e = blockIdx.x * 256 + threadIdx.x; e < N_EDGES; e += HBLK * 256)
        atomicAdd(&h[src[e] >> 8], 1);
    __syncthreads();
    for (int i = threadIdx.x; i < NBUCK; i += 256) {
        int c = h[i];
        cur[i] = sBase[i] + (c ? atomicAdd(&sRes[i], c) : 0);
    }
    __syncthreads();
    for (int e = blockIdx.x * 256 + threadIdx.x; e < N_EDGES; e += HBLK * 256) {
        int s = src[e];
        int p = atomicAdd(&cur[s >> 8], 1);   // LDS atomic
        bslo[p] = (unsigned char)(s & 255);
    }
}

// ---------------- K4: fine per dst-bucket: ideg, rs, inorm, sorted src ----------------

__global__ __launch_bounds__(256) void fine_dst_kernel(
    const int* __restrict__ dBase, const unsigned char* __restrict__ bdlo,
    const int* __restrict__ bsrc, int* __restrict__ rs, float* __restrict__ inorm,
    int* __restrict__ ssrc) {
    __shared__ int hist[256], scn[256], cur[256];
    int t = threadIdx.x, b = blockIdx.x;
    int lo = dBase[b], hi = dBase[b + 1];
    hist[t] = 0;
    __syncthreads();
    for (int p = lo + t; p < hi; p += 256) atomicAdd(&hist[bdlo[p]], 1);
    __syncthreads();
    int v = hist[t];
    scn[t] = v;
    __syncthreads();
    for (int s = 1; s < 256; s <<= 1) {
        int u = (t >= s) ? scn[t - s] : 0;
        __syncthreads();
        scn[t] += u;
        __syncthreads();
    }
    int excl = scn[t] - v;
    cur[t] = lo + excl;
    int node = b * 256 + t;
    if (node < N_NODES) {
        rs[node] = lo + excl;
        inorm[node] = 1.0f / sqrtf((float)max(v, 1));
    }
    if (b == 0 && t == 0) rs[N_NODES] = N_EDGES;
    __syncthreads();
    for (int p = lo + t; p < hi; p += 256) {
        int slot = atomicAdd(&cur[bdlo[p]], 1);   // LDS atomic
        ssrc[slot] = bsrc[p];
    }
}

// ---------------- K5: fine per src-bucket: odeg -> onorm ----------------

__global__ __launch_bounds__(256) void fine_src_kernel(
    const int* __restrict__ sBase, const unsigned char* __restrict__ bslo,
    float* __restrict__ onorm) {
    __shared__ int hist[256];
    int t = threadIdx.x, b = blockIdx.x;
    int lo = sBase[b], hi = sBase[b + 1];
    hist[t] = 0;
    __syncthreads();
    for (int p = lo + t; p < hi; p += 256) atomicAdd(&hist[bslo[p]], 1);
    __syncthreads();
    int node = b * 256 + t;
    if (node < N_NODES) onorm[node] = 1.0f / sqrtf((float)max(hist[t], 1));
}

// ---------------- GEMM1: h1 = (x * out_norm) @ W1   [N,256]@[256,64] ----------------

__global__ __launch_bounds__(256) void gemm1_kernel(
    const float* __restrict__ x, const float* __restrict__ W,
    const float* __restrict__ onorm, float* __restrict__ h, int n) {
    __shared__ float As[16][64];
    __shared__ float Ws[16][64];
    const int tid = threadIdx.x;
    const int tx = tid & 15;
    const int ty = tid >> 4;
    const int rowBase = blockIdx.x * 64;

    const int lr = tid >> 2;
    const int lk = (tid & 3) * 4;
    const int lrow = rowBase + lr;
    const bool lvalid = (lrow < n);
    const float lscale = lvalid ? onorm[lrow] : 0.0f;
    const int wk = tid >> 4;
    const int wc = (tid & 15) * 4;

    float acc[4][4] = {};

    for (int k0 = 0; k0 < 256; k0 += 16) {
        float4 v = make_float4(0.f, 0.f, 0.f, 0.f);
        if (lvalid) v = *(const float4*)(x + (size_t)lrow * 256 + k0 + lk);
        As[lk + 0][lr] = v.x * lscale;
        As[lk + 1][lr] = v.y * lscale;
        As[lk + 2][lr] = v.z * lscale;
        As[lk + 3][lr] = v.w * lscale;
        *(float4*)&Ws[wk][wc] = *(const float4*)(W + (size_t)(k0 + wk) * 64 + wc);
        __syncthreads();
#pragma unroll
        for (int k = 0; k < 16; ++k) {
            float4 a = *(const float4*)&As[k][ty * 4];
            float4 b = *(const float4*)&Ws[k][tx * 4];
            float av[4] = {a.x, a.y, a.z, a.w};
            float bv[4] = {b.x, b.y, b.z, b.w};
#pragma unroll
            for (int i = 0; i < 4; ++i)
#pragma unroll
                for (int j = 0; j < 4; ++j) acc[i][j] += av[i] * bv[j];
        }
        __syncthreads();
    }
#pragma unroll
    for (int i = 0; i < 4; ++i) {
        int row = rowBase + ty * 4 + i;
        if (row < n) {
            *(float4*)(h + (size_t)row * 64 + tx * 4) =
                make_float4(acc[i][0], acc[i][1], acc[i][2], acc[i][3]);
        }
    }
}

// ---------------- agg layer1: wave per node, 4 edges x 16 float4-lanes ----------------

__global__ __launch_bounds__(256) void agg64_kernel(
    const int* __restrict__ rs, const int* __restrict__ ss,
    const float* __restrict__ h, float* __restrict__ agg, int n) {
    int node = (blockIdx.x * blockDim.x + threadIdx.x) >> 6;
    if (node >= n) return;
    int lane = threadIdx.x & 63;
    int q = lane >> 4;
    int f = lane & 15;
    int beg = rs[node], end = rs[node + 1];
    float4 a0 = {0.f, 0.f, 0.f, 0.f}, a1 = {0.f, 0.f, 0.f, 0.f};
    int j = beg;
    for (; j + 8 <= end; j += 8) {
        int s0 = ss[j + q];
        int s1 = ss[j + 4 + q];
        float4 v0 = *((const float4*)(h + (size_t)s0 * 64) + f);
        float4 v1 = *((const float4*)(h + (size_t)s1 * 64) + f);
        a0.x += v0.x; a0.y += v0.y; a0.z += v0.z; a0.w += v0.w;
        a1.x += v1.x; a1.y += v1.y; a1.z += v1.z; a1.w += v1.w;
    }
    for (; j + 4 <= end; j += 4) {
        int s0 = ss[j + q];
        float4 v0 = *((const float4*)(h + (size_t)s0 * 64) + f);
        a0.x += v0.x; a0.y += v0.y; a0.z += v0.z; a0.w += v0.w;
    }
    if (j + q < end) {
        int s0 = ss[j + q];
        float4 v0 = *((const float4*)(h + (size_t)s0 * 64) + f);
        a0.x += v0.x; a0.y += v0.y; a0.z += v0.z; a0.w += v0.w;
    }
    a0.x += a1.x; a0.y += a1.y; a0.z += a1.z; a0.w += a1.w;
    a0.x += __shfl_xor(a0.x, 16); a0.y += __shfl_xor(a0.y, 16);
    a0.z += __shfl_xor(a0.z, 16); a0.w += __shfl_xor(a0.w, 16);
    a0.x += __shfl_xor(a0.x, 32); a0.y += __shfl_xor(a0.y, 32);
    a0.z += __shfl_xor(a0.z, 32); a0.w += __shfl_xor(a0.w, 32);
    if (q == 0) ((float4*)(agg + (size_t)node * 64))[f] = a0;
}

// ---------------- GEMM2: h2 = ((agg*in_norm + b1) * out_norm) @ W2  [N,64]@[64,40] ----

__global__ __launch_bounds__(256) void gemm2_kernel(
    const float* __restrict__ agg, const float* __restrict__ W2,
    const float* __restrict__ b1, const float* __restrict__ inorm,
    const float* __restrict__ onorm, float* __restrict__ h2, int n) {
    __shared__ float Ws[64 * 40];
    int tid = threadIdx.x;
    for (int i = tid; i < 64 * 40; i += 256) Ws[i] = W2[i];
    __syncthreads();
    int lane = tid & 63;
    int wave = tid >> 6;
    int step = gridDim.x * 4;
    for (int row = blockIdx.x * 4 + wave; row < n; row += step) {
        float so  = onorm[row];
        float s12 = inorm[row] * so;
        const float* ar = agg + (size_t)row * 64;
        if (lane < 40) {
            float acc = 0.f;
#pragma unroll
            for (int k = 0; k < 64; ++k) {
                float xv = ar[k] * s12 + b1[k] * so;
                acc += xv * Ws[k * 40 + lane];
            }
            h2[(size_t)row * 40 + lane] = acc;
        }
    }
}

// ---------------- agg layer2 + epilogue: out = agg2 * in_norm + b2 ----------------

__global__ __launch_bounds__(256) void agg40_kernel(
    const int* __restrict__ rs, const int* __restrict__ ss,
    const float* __restrict__ h2, const float* __restrict__ inorm,
    const float* __restrict__ b2, float* __restrict__ out, int n) {
    int node = (blockIdx.x * blockDim.x + threadIdx.x) >> 6;
    if (node >= n) return;
    int lane = threadIdx.x & 63;
    int q = lane >> 4;
    int f = lane & 15;
    bool act = (f < 10);
    int beg = rs[node], end = rs[node + 1];
    float4 a0 = {0.f, 0.f, 0.f, 0.f}, a1 = {0.f, 0.f, 0.f, 0.f};
    int j = beg;
    for (; j + 8 <= end; j += 8) {
        int s0 = ss[j + q];
        int s1 = ss[j + 4 + q];
        if (act) {
            float4 v0 = *((const float4*)(h2 + (size_t)s0 * 40) + f);
            float4 v1 = *((const float4*)(h2 + (size_t)s1 * 40) + f);
            a0.x += v0.x; a0.y += v0.y; a0.z += v0.z; a0.w += v0.w;
            a1.x += v1.x; a1.y += v1.y; a1.z += v1.z; a1.w += v1.w;
        }
    }
    for (; j + 4 <= end; j += 4) {
        int s0 = ss[j + q];
        if (act) {
            float4 v0 = *((const float4*)(h2 + (size_t)s0 * 40) + f);
            a0.x += v0.x; a0.y += v0.y; a0.z += v0.z; a0.w += v0.w;
        }
    }
    if (j + q < end && act) {
        int s0 = ss[j + q];
        float4 v0 = *((const float4*)(h2 + (size_t)s0 * 40) + f);
        a0.x += v0.x; a0.y += v0.y; a0.z += v0.z; a0.w += v0.w;
    }
    a0.x += a1.x; a0.y += a1.y; a0.z += a1.z; a0.w += a1.w;
    a0.x += __shfl_xor(a0.x, 16); a0.y += __shfl_xor(a0.y, 16);
    a0.z += __shfl_xor(a0.z, 16); a0.w += __shfl_xor(a0.w, 16);
    a0.x += __shfl_xor(a0.x, 32); a0.y += __shfl_xor(a0.y, 32);
    a0.z += __shfl_xor(a0.z, 32); a0.w += __shfl_xor(a0.w, 32);
    if (q == 0 && act) {
        float s = inorm[node];
        float4 vb = ((const float4*)b2)[f];
        float4 r;
        r.x = a0.x * s + vb.x; r.y = a0.y * s + vb.y;
        r.z = a0.z * s + vb.z; r.w = a0.w * s + vb.w;
        ((float4*)(out + (size_t)node * 40))[f] = r;
    }
}

extern "C" void kernel_launch(void* const* d_in, const int* in_sizes, int n_in,
                              void* d_out, int out_size, void* d_ws, size_t ws_size,
                              hipStream_t stream) {
    const float* x  = (const float*)d_in[0];
    const int* src  = (const int*)d_in[1];
    const int* dst  = (const int*)d_in[2];
    const float* W1 = (const float*)d_in[3];
    const float* b1 = (const float*)d_in[4];
    const float* W2 = (const float*)d_in[5];
    const float* b2 = (const float*)d_in[6];
    float* out = (float*)d_out;

    char* wsb = (char*)d_ws;
    size_t off = 0;
    auto alloc = [&](size_t bytes) { char* p = wsb + off; off += (bytes + 255) & ~size_t(255); return p; };

    int*   zeroed = (int*)  alloc(4 * NBUCK * 4);        // gHD | gHS | dRes | sRes
    int*   gHD    = zeroed;
    int*   gHS    = zeroed + NBUCK;
    int*   dRes   = zeroed + 2 * NBUCK;
    int*   sRes   = zeroed + 3 * NBUCK;
    int*   dBase  = (int*)  alloc((NBUCK + 1) * 4);
    int*   sBase  = (int*)  alloc((NBUCK + 1) * 4);
    float* onorm  = (float*)alloc(N_NODES * 4);
    float* inorm  = (float*)alloc(N_NODES * 4);
    int*   rs     = (int*)  alloc((N_NODES + 1) * 4);
    int*   ssrc   = (int*)  alloc((size_t)N_EDGES * 4);
    float* h1     = (float*)alloc((size_t)N_NODES * 64 * 4);  // reused as h2 (N*40)
    float* agg1   = (float*)alloc((size_t)N_NODES * 64 * 4);
    float* h2 = h1;
    // bucket staging arrays alias agg1 (agg1 is first written by agg64, after K4/K5)
    int* bsrc = (int*)agg1;                                     // E ints
    unsigned char* bdlo = (unsigned char*)(bsrc + N_EDGES);     // E bytes
    unsigned char* bslo = bdlo + N_EDGES;                       // E bytes

    hipMemsetAsync(zeroed, 0, 4 * NBUCK * 4, stream);

    coarse_hist_kernel<<<HBLK, 256, 0, stream>>>(src, dst, gHD, gHS);
    coarse_scan_kernel<<<1, 512, 0, stream>>>(gHD, gHS, dBase, sBase);
    scatter_dst_kernel<<<HBLK, 256, 0, stream>>>(src, dst, dBase, dRes, bsrc, bdlo);
    scatter_src_kernel<<<HBLK, 256, 0, stream>>>(src, sBase, sRes, bslo);
    fine_dst_kernel<<<NBUCK, 256, 0, stream>>>(dBase, bdlo, bsrc, rs, inorm, ssrc);
    fine_src_kernel<<<NBUCK, 256, 0, stream>>>(sBase, bslo, onorm);

    gemm1_kernel<<<(N_NODES + 63) / 64, 256, 0, stream>>>(x, W1, onorm, h1, N_NODES);

    agg64_kernel<<<(N_NODES * 64) / 256, 256, 0, stream>>>(rs, ssrc, h1, agg1, N_NODES);

    gemm2_kernel<<<2048, 256, 0, stream>>>(agg1, W2, b1, inorm, onorm, h2, N_NODES);

    agg40_kernel<<<(N_NODES * 64) / 256, 256, 0, stream>>>(rs, ssrc, h2, inorm, b2, out, N_NODES);
}